// Round 1
// baseline (323.137 us; speedup 1.0000x reference)
//
#include <hip/hip_runtime.h>

#define BLOCK 128

// Forward layer: reads K activations from this thread's LDS column, computes
// N outputs in registers (weights/biases are wave-uniform -> s_load), applies
// ReLU, records the >0 mask, and overwrites the LDS column with the outputs.
template<int K, int N>
__device__ __forceinline__ unsigned long long fwd_layer(
    const float* __restrict__ W, const float* __restrict__ b,
    float* buf, int tid)
{
    float acc[N];
#pragma unroll
    for (int j = 0; j < N; ++j) acc[j] = b[j];
#pragma unroll 4
    for (int k = 0; k < K; ++k) {
        const float c = buf[k * BLOCK + tid];
#pragma unroll
        for (int j = 0; j < N; ++j) acc[j] = fmaf(c, W[k * N + j], acc[j]);
    }
    unsigned long long m = 0ULL;
#pragma unroll
    for (int j = 0; j < N; ++j) {
        const bool p = acc[j] > 0.0f;
        m |= ((unsigned long long)(p ? 1 : 0)) << j;
        buf[j * BLOCK + tid] = p ? acc[j] : 0.0f;
    }
    return m;
}

// Tangent layer: same matmul, but masked by the forward ReLU mask (no bias).
template<int K, int N>
__device__ __forceinline__ void tan_layer(
    const float* __restrict__ W, float* buf, int tid, unsigned long long m)
{
    float acc[N];
#pragma unroll
    for (int j = 0; j < N; ++j) acc[j] = 0.0f;
#pragma unroll 4
    for (int k = 0; k < K; ++k) {
        const float c = buf[k * BLOCK + tid];
#pragma unroll
        for (int j = 0; j < N; ++j) acc[j] = fmaf(c, W[k * N + j], acc[j]);
    }
#pragma unroll
    for (int j = 0; j < N; ++j)
        buf[j * BLOCK + tid] = ((m >> j) & 1ULL) ? acc[j] : 0.0f;
}

__global__ __launch_bounds__(BLOCK)
void mlp_jac_kernel(
    const float* __restrict__ W1, const float* __restrict__ b1,
    const float* __restrict__ W2, const float* __restrict__ b2,
    const float* __restrict__ W3, const float* __restrict__ b3,
    const float* __restrict__ W4, const float* __restrict__ b4,
    const float* __restrict__ W5, const float* __restrict__ b5,
    const float* __restrict__ xin,
    float* __restrict__ out_state, float* __restrict__ out_F, int Btot)
{
    // Per-thread private LDS column: buf[k*BLOCK + tid], k in [0,64).
    // 64 * 128 * 4B = 32 KB per block. No cross-thread sharing -> no barriers.
    __shared__ float buf[64 * BLOCK];
    const int tid = threadIdx.x;
    const int s = blockIdx.x * BLOCK + tid;
    if (s >= Btot) return;

    const float4 xv = *reinterpret_cast<const float4*>(xin + 4 * s);
    const float xa[4] = {xv.x, xv.y, xv.z, xv.w};

    // ---------------- forward (fp32, exact masks) ----------------
    unsigned long long m1, m2, m3, m4;
    {
        float acc[32];
#pragma unroll
        for (int j = 0; j < 32; ++j) {
            float a = b1[j];
#pragma unroll
            for (int k = 0; k < 4; ++k) a = fmaf(xa[k], W1[k * 32 + j], a);
            acc[j] = a;
        }
        unsigned long long m = 0ULL;
#pragma unroll
        for (int j = 0; j < 32; ++j) {
            const bool p = acc[j] > 0.0f;
            m |= ((unsigned long long)(p ? 1 : 0)) << j;
            buf[j * BLOCK + tid] = p ? acc[j] : 0.0f;
        }
        m1 = m;
    }
    m2 = fwd_layer<32, 32>(W2, b2, buf, tid);
    m3 = fwd_layer<32, 64>(W3, b3, buf, tid);
    m4 = fwd_layer<64, 64>(W4, b4, buf, tid);
    {
        float y[4] = {b5[0], b5[1], b5[2], b5[3]};
#pragma unroll 8
        for (int k = 0; k < 64; ++k) {
            const float c = buf[k * BLOCK + tid];
#pragma unroll
            for (int j = 0; j < 4; ++j) y[j] = fmaf(c, W5[k * 4 + j], y[j]);
        }
        float4 o;
        o.x = xa[0] + y[0];
        o.y = xa[1] + y[1];
        o.z = xa[2] + y[2];
        o.w = xa[3] + y[3];
        *reinterpret_cast<float4*>(out_state + 4 * s) = o;
    }

    // ---------------- Jacobian columns (forward-mode, tangent e_r) --------
    // Column r of J_mlp: t = (e_r @ W1) .* m1 -> ... -> y = t4 @ W5.
    // F[s][i][r] = (i==r) + y[i]   (jacfwd layout: [out_dim][in_dim])
    for (int r = 0; r < 4; ++r) {
#pragma unroll
        for (int j = 0; j < 32; ++j)
            buf[j * BLOCK + tid] = ((m1 >> j) & 1ULL) ? W1[r * 32 + j] : 0.0f;
        tan_layer<32, 32>(W2, buf, tid, m2);
        tan_layer<32, 64>(W3, buf, tid, m3);
        tan_layer<64, 64>(W4, buf, tid, m4);
        float y[4] = {0.0f, 0.0f, 0.0f, 0.0f};
#pragma unroll 8
        for (int k = 0; k < 64; ++k) {
            const float c = buf[k * BLOCK + tid];
#pragma unroll
            for (int j = 0; j < 4; ++j) y[j] = fmaf(c, W5[k * 4 + j], y[j]);
        }
#pragma unroll
        for (int i = 0; i < 4; ++i)
            out_F[(size_t)s * 16 + i * 4 + r] = y[i] + (i == r ? 1.0f : 0.0f);
    }
}

extern "C" void kernel_launch(void* const* d_in, const int* in_sizes, int n_in,
                              void* d_out, int out_size, void* d_ws, size_t ws_size,
                              hipStream_t stream)
{
    const float* W1 = (const float*)d_in[0];
    const float* b1 = (const float*)d_in[1];
    const float* W2 = (const float*)d_in[2];
    const float* b2 = (const float*)d_in[3];
    const float* W3 = (const float*)d_in[4];
    const float* b3 = (const float*)d_in[5];
    const float* W4 = (const float*)d_in[6];
    const float* b4 = (const float*)d_in[7];
    const float* W5 = (const float*)d_in[8];
    const float* b5 = (const float*)d_in[9];
    const float* xin = (const float*)d_in[10];
    // d_in[11] = training flag (unused; reference output independent of it)

    const int Btot = in_sizes[10] / 4;  // last_state is (B,1,4) fp32
    float* out_state = (float*)d_out;
    float* out_F = out_state + (size_t)Btot * 4;

    const int grid = (Btot + BLOCK - 1) / BLOCK;
    mlp_jac_kernel<<<grid, BLOCK, 0, stream>>>(
        W1, b1, W2, b2, W3, b3, W4, b4, W5, b5, xin, out_state, out_F, Btot);
}

// Round 2
// 141.270 us; speedup vs baseline: 2.2874x; 2.2874x over previous
//
#include <hip/hip_runtime.h>

typedef __attribute__((ext_vector_type(8))) short short8;
typedef __attribute__((ext_vector_type(4))) float f32x4;

#define NWAVES 2
#define BLOCK (64 * NWAVES)
#define TBYTES 16384                 // 128 rows x 128 B bf16 tangent/act buffer
#define MWORDS 6                     // mask u32 words per sample: m1,m2,m3lo,m3hi,m4lo,m4hi
#define WBYTES (TBYTES + 64 * MWORDS * 4)

__device__ __forceinline__ unsigned short f2bf(float f) {
    unsigned u = __builtin_bit_cast(unsigned, f);
    u += 0x7FFFu + ((u >> 16) & 1u);           // round-to-nearest-even
    return (unsigned short)(u >> 16);
}

// Build a bf16 B-fragment for mfma_f32_16x16x32_bf16.
// B[k][n], k = kbase..kbase+7 (lane group picks kbase), n = col. Zero-padded.
__device__ __forceinline__ short8 loadB(const float* __restrict__ W, int Nout, int Kin,
                                        int kbase, int col) {
    short8 r;
#pragma unroll
    for (int i = 0; i < 8; ++i) {
        int k = kbase + i;
        float v = (k < Kin && col < Nout) ? W[k * Nout + col] : 0.0f;
        r[i] = (short)f2bf(v);
    }
    return r;
}

// ---------------- scalar fp32 forward (exact masks) ----------------
template<int K, int N>
__device__ __forceinline__ unsigned long long fwd_layer(
    const float* __restrict__ W, const float* __restrict__ b,
    float* fbuf, int lane)
{
    float acc[N];
#pragma unroll
    for (int j = 0; j < N; ++j) acc[j] = b[j];
#pragma unroll 4
    for (int k = 0; k < K; ++k) {
        const float cv = fbuf[k * 64 + lane];
#pragma unroll
        for (int j = 0; j < N; ++j) acc[j] = fmaf(cv, W[k * N + j], acc[j]);
    }
    unsigned long long m = 0ULL;
#pragma unroll
    for (int j = 0; j < N; ++j) {
        const bool p = acc[j] > 0.0f;
        m |= ((unsigned long long)(p ? 1 : 0)) << j;
        fbuf[j * 64 + lane] = p ? acc[j] : 0.0f;
    }
    return m;
}

// ---------------- tangent epilogue: mask, cvt bf16, swizzled LDS write -------
// C/D layout (verified): col = lane&15, row = (lane>>4)*4 + reg.
template<int MBASE, int M64>
__device__ __forceinline__ void epi_store(unsigned char* wb, const unsigned* mk,
                                          f32x4 c, int mt, int nt, int lane)
{
    const int col = lane & 15, G = lane >> 4;
    const int unit = nt * 16 + col;
    const int word = MBASE + (M64 ? (unit >> 5) : 0);
    const int bit  = M64 ? (unit & 31) : unit;
    const int R0 = mt * 16 + G * 4;
    const int s0 = R0 >> 1;                       // row R = 2*s + rr
    const unsigned mw0 = mk[s0 * MWORDS + word];
    const unsigned mw1 = mk[(s0 + 1) * MWORDS + word];
    const int slotbase = unit >> 3;
    const int off = (unit & 7) * 2;
#pragma unroll
    for (int i = 0; i < 4; ++i) {
        const int R = R0 + i;
        const unsigned mw = (i < 2) ? mw0 : mw1;
        const float v = ((mw >> bit) & 1u) ? c[i] : 0.0f;
        const int byte = R * 128 + (((slotbase ^ (R & 7)) << 4) | off);
        *(unsigned short*)(wb + byte) = f2bf(v);
    }
}

// ---------------- one tangent GEMM layer, in-place in the T buffer ----------
// A[row][k] read from T rows (row = lane&15 + 16*mt, k from slot 4*kt+G),
// B = weight fragments. K-labeling cancels between A and B.
template<int KT, int NT, int MBASE, int M64>
__device__ __forceinline__ void tan_layer_mfma(unsigned char* wb, const unsigned* mk,
                                               const short8* Bf, int lane)
{
    const int G = lane >> 4;
    const int r15 = lane & 15;
#pragma unroll 2
    for (int mt = 0; mt < 8; ++mt) {
        const int R = mt * 16 + r15;
        short8 a[KT];
#pragma unroll
        for (int kt = 0; kt < KT; ++kt)
            a[kt] = *(const short8*)(wb + R * 128 + (((4 * kt + G) ^ (r15 & 7)) << 4));
#pragma unroll
        for (int nt = 0; nt < NT; ++nt) {
            f32x4 c = {0.f, 0.f, 0.f, 0.f};
#pragma unroll
            for (int kt = 0; kt < KT; ++kt)
                c = __builtin_amdgcn_mfma_f32_16x16x32_bf16(a[kt], Bf[kt * NT + nt], c, 0, 0, 0);
            epi_store<MBASE, M64>(wb, mk, c, mt, nt, lane);
        }
    }
}

// ---------------- final layer: T4 @ W5 -> F (adds identity) -----------------
__device__ __forceinline__ void tan_final(unsigned char* wb, const short8* B5,
                                          int lane, int rbase,
                                          float* __restrict__ out_F, int sbase)
{
    const int G = lane >> 4, col = lane & 15;
    const int r15 = lane & 15;
#pragma unroll 2
    for (int mt = 0; mt < 8; ++mt) {
        const int R = mt * 16 + r15;
        short8 a0 = *(const short8*)(wb + R * 128 + (((0 + G) ^ (r15 & 7)) << 4));
        short8 a1 = *(const short8*)(wb + R * 128 + (((4 + G) ^ (r15 & 7)) << 4));
        f32x4 c = {0.f, 0.f, 0.f, 0.f};
        c = __builtin_amdgcn_mfma_f32_16x16x32_bf16(a0, B5[0], c, 0, 0, 0);
        c = __builtin_amdgcn_mfma_f32_16x16x32_bf16(a1, B5[1], c, 0, 0, 0);
        if (col < 4) {
            const int R0 = mt * 16 + G * 4;
#pragma unroll
            for (int i = 0; i < 4; ++i) {
                const int Rw = R0 + i;
                const int s = Rw >> 1;
                const int r = rbase + (Rw & 1);
                const float v = c[i] + ((col == r) ? 1.0f : 0.0f);
                out_F[(size_t)(sbase + s) * 16 + col * 4 + r] = v;
            }
        }
    }
}

__global__ __launch_bounds__(BLOCK)
void mlp_jac_kernel(
    const float* __restrict__ W1, const float* __restrict__ b1,
    const float* __restrict__ W2, const float* __restrict__ b2,
    const float* __restrict__ W3, const float* __restrict__ b3,
    const float* __restrict__ W4, const float* __restrict__ b4,
    const float* __restrict__ W5, const float* __restrict__ b5,
    const float* __restrict__ xin,
    float* __restrict__ out_state, float* __restrict__ out_F, int Btot)
{
    __shared__ __align__(16) unsigned char smem[NWAVES][WBYTES];
    const int tid = threadIdx.x;
    const int wid = tid >> 6;
    const int lane = tid & 63;
    const int sbase = blockIdx.x * BLOCK + wid * 64;   // wave's first sample
    if (sbase >= Btot) return;

    unsigned char* wb = smem[wid];
    float* fbuf = (float*)wb;                          // fwd acts, [unit*64+lane] fp32
    unsigned* mk = (unsigned*)(wb + TBYTES);           // masks

    const int s_my = sbase + lane;
    const float4 xv = *reinterpret_cast<const float4*>(xin + 4 * s_my);
    const float xa[4] = {xv.x, xv.y, xv.z, xv.w};

    // ================= phase 1: fp32 forward, masks, new_state =============
    unsigned m1;
    {
        float acc[32];
#pragma unroll
        for (int j = 0; j < 32; ++j) {
            float a = b1[j];
#pragma unroll
            for (int k = 0; k < 4; ++k) a = fmaf(xa[k], W1[k * 32 + j], a);
            acc[j] = a;
        }
        unsigned m = 0;
#pragma unroll
        for (int j = 0; j < 32; ++j) {
            const bool p = acc[j] > 0.0f;
            m |= ((unsigned)(p ? 1 : 0)) << j;
            fbuf[j * 64 + lane] = p ? acc[j] : 0.0f;
        }
        m1 = m;
    }
    const unsigned m2 = (unsigned)fwd_layer<32, 32>(W2, b2, fbuf, lane);
    const unsigned long long m3 = fwd_layer<32, 64>(W3, b3, fbuf, lane);
    const unsigned long long m4 = fwd_layer<64, 64>(W4, b4, fbuf, lane);
    {
        float y[4] = {b5[0], b5[1], b5[2], b5[3]};
#pragma unroll 8
        for (int k = 0; k < 64; ++k) {
            const float cv = fbuf[k * 64 + lane];
#pragma unroll
            for (int j = 0; j < 4; ++j) y[j] = fmaf(cv, W5[k * 4 + j], y[j]);
        }
        float4 o;
        o.x = xa[0] + y[0]; o.y = xa[1] + y[1];
        o.z = xa[2] + y[2]; o.w = xa[3] + y[3];
        *reinterpret_cast<float4*>(out_state + 4 * s_my) = o;
    }
    {
        unsigned* mks = mk + lane * MWORDS;
        mks[0] = m1;
        mks[1] = m2;
        mks[2] = (unsigned)(m3 & 0xffffffffULL);
        mks[3] = (unsigned)(m3 >> 32);
        mks[4] = (unsigned)(m4 & 0xffffffffULL);
        mks[5] = (unsigned)(m4 >> 32);
    }

    // ================= phase 2: bf16 weight B-fragments in registers =======
    const int col = lane & 15, G = lane >> 4;
    short8 B1f[2], B2f[2], B3f[4], B4f[8], B5f[2];
#pragma unroll
    for (int nt = 0; nt < 2; ++nt) B1f[nt] = loadB(W1, 32, 4, 8 * G, 16 * nt + col);
#pragma unroll
    for (int nt = 0; nt < 2; ++nt) B2f[nt] = loadB(W2, 32, 32, 8 * G, 16 * nt + col);
#pragma unroll
    for (int nt = 0; nt < 4; ++nt) B3f[nt] = loadB(W3, 64, 32, 8 * G, 16 * nt + col);
#pragma unroll
    for (int kt = 0; kt < 2; ++kt)
#pragma unroll
        for (int nt = 0; nt < 4; ++nt)
            B4f[kt * 4 + nt] = loadB(W4, 64, 64, 32 * kt + 8 * G, 16 * nt + col);
#pragma unroll
    for (int kt = 0; kt < 2; ++kt) B5f[kt] = loadB(W5, 4, 64, 32 * kt + 8 * G, col);

    // ================= phase 3: tangent passes (jac cols {0,1} then {2,3}) ==
    for (int rbase = 0; rbase < 4; rbase += 2) {
        // ---- T1 = m1 .* (E @ W1): one-hot A built in-register ----
        short8 ae = {0, 0, 0, 0, 0, 0, 0, 0};
        if (G == 0) {
            const int ksel = rbase + (lane & 1);    // row R parity picks jac col
#pragma unroll
            for (int i = 0; i < 4; ++i) if (i == ksel) ae[i] = (short)0x3F80;
        }
#pragma unroll 2
        for (int mt = 0; mt < 8; ++mt) {
#pragma unroll
            for (int nt = 0; nt < 2; ++nt) {
                f32x4 c = {0.f, 0.f, 0.f, 0.f};
                c = __builtin_amdgcn_mfma_f32_16x16x32_bf16(ae, B1f[nt], c, 0, 0, 0);
                epi_store<0, 0>(wb, mk, c, mt, nt, lane);
            }
        }
        // ---- T2 = m2 .* (T1 @ W2), T3 = m3 .* (T2 @ W3), T4 = m4 .* (T3 @ W4)
        tan_layer_mfma<1, 2, 1, 0>(wb, mk, B2f, lane);
        tan_layer_mfma<1, 4, 2, 1>(wb, mk, B3f, lane);
        tan_layer_mfma<2, 4, 4, 1>(wb, mk, B4f, lane);
        // ---- F = I + T4 @ W5 ----
        tan_final(wb, B5f, lane, rbase, out_F, sbase);
    }
}

extern "C" void kernel_launch(void* const* d_in, const int* in_sizes, int n_in,
                              void* d_out, int out_size, void* d_ws, size_t ws_size,
                              hipStream_t stream)
{
    const float* W1 = (const float*)d_in[0];
    const float* b1 = (const float*)d_in[1];
    const float* W2 = (const float*)d_in[2];
    const float* b2 = (const float*)d_in[3];
    const float* W3 = (const float*)d_in[4];
    const float* b3 = (const float*)d_in[5];
    const float* W4 = (const float*)d_in[6];
    const float* b4 = (const float*)d_in[7];
    const float* W5 = (const float*)d_in[8];
    const float* b5 = (const float*)d_in[9];
    const float* xin = (const float*)d_in[10];

    const int Btot = in_sizes[10] / 4;       // last_state is (B,1,4) fp32
    float* out_state = (float*)d_out;
    float* out_F = out_state + (size_t)Btot * 4;

    const int grid = (Btot + BLOCK - 1) / BLOCK;
    mlp_jac_kernel<<<grid, BLOCK, 0, stream>>>(
        W1, b1, W2, b2, W3, b3, W4, b4, W5, b5, xin, out_state, out_F, Btot);
}